// Round 12
// baseline (172.740 us; speedup 1.0000x reference)
//
#include <hip/hip_runtime.h>
#include <math.h>

#define BATCH   4
#define S_LEN   2048
#define DMODEL  512
#define NHEADS  8
#define DHEAD   64
#define M_TOT   8192
#define ATT_SCALE 0.04419417382415922f   // 1/sqrt(512)
#define QSCALE (ATT_SCALE * 1.44269504088896f)  // fold log2(e): exp2 in softmax

using short8  = __attribute__((ext_vector_type(8))) short;
using short4v = __attribute__((ext_vector_type(4))) short;
using floatx4 = __attribute__((ext_vector_type(4))) float;

// fp32 -> bf16 RNE
__device__ __forceinline__ ushort f2bf(float f) {
    union { float f; unsigned u; } x; x.f = f;
    unsigned u = x.u + 0x7FFFu + ((x.u >> 16) & 1u);
    return (ushort)(u >> 16);
}
__device__ __forceinline__ unsigned pk2(float a, float b) {
    return (unsigned)f2bf(a) | ((unsigned)f2bf(b) << 16);
}
// fp32x2 -> packed bf16x2, round-half-up — hot-loop use
__device__ __forceinline__ unsigned pkr2(float a, float b) {
    unsigned ua = __float_as_uint(a) + 0x8000u;
    unsigned ub = __float_as_uint(b) + 0x8000u;
    return __builtin_amdgcn_perm(ub, ua, 0x07060302u);
}

// ---------------------------------------------------------------------------
// Preprocess: blocks [0,4096) x fp32->bf16; [4096,4352) W transpose to bf16.
// ---------------------------------------------------------------------------
__global__ __launch_bounds__(256) void prep(
    const float* __restrict__ x,
    const float* __restrict__ Wq, const float* __restrict__ Wk,
    const float* __restrict__ Wv, const float* __restrict__ Wo,
    ushort* __restrict__ xb, ushort* __restrict__ WT)
{
    const int bid = blockIdx.x;
    if (bid < 4096) {
        const int i = (bid * 256 + threadIdx.x) * 4;
        float4 f = *(const float4*)(x + i);
        uint2 o; o.x = pk2(f.x, f.y); o.y = pk2(f.z, f.w);
        *(uint2*)(xb + i) = o;
    } else {
        const int rb = bid - 4096;
        const int p  = rb >> 6;
        const int rem = rb & 63;
        const int n  = (rem >> 5) * 256 + threadIdx.x;
        const int k0 = (rem & 31) * 16;
        const float* W = (p == 0) ? Wq : (p == 1) ? Wk : (p == 2) ? Wv : Wo;
        unsigned u[8];
        #pragma unroll
        for (int j = 0; j < 8; ++j) {
            float a = W[(k0 + 2 * j)     * DMODEL + n];
            float b = W[(k0 + 2 * j + 1) * DMODEL + n];
            u[j] = pk2(a, b);
        }
        ushort* dst = WT + ((size_t)p * DMODEL + n) * DMODEL + k0;
        *(uint4*)dst       = *(uint4*)&u[0];
        *(uint4*)(dst + 8) = *(uint4*)&u[4];
    }
}

// ---------------------------------------------------------------------------
// Kernel 1: fused QKV projection — r4 version verbatim (padded LDS, VGPR
// register prefetch; ~19-24 µs via r7 triple-launch probe).
// ---------------------------------------------------------------------------
__global__ __launch_bounds__(256, 4) void qkv_gemm(
    const ushort* __restrict__ xb, const ushort* __restrict__ WT,
    const float* __restrict__ bq, const float* __restrict__ bk, const float* __restrict__ bv,
    ushort* __restrict__ q, ushort* __restrict__ k, ushort* __restrict__ vT)
{
    __shared__ ushort SMEM[128 * 136];   // K-loop A+B (20.5 KB); CT overlay
    ushort (*A)[40] = (ushort(*)[40])SMEM;
    ushort (*B)[40] = (ushort(*)[40])(SMEM + 128 * 40);
    ushort (*CT)[136] = (ushort(*)[136])SMEM;

    const int tid = threadIdx.x;
    const int wv  = tid >> 6, lane = tid & 63, l16 = lane & 15, quad = lane >> 4;
    const int m0  = blockIdx.x * 128;
    const int ng0 = blockIdx.y * 128;
    const int p   = ng0 >> 9;
    const int n0  = ng0 & 511;
    const ushort* Wp  = WT + (size_t)p * DMODEL * DMODEL + (size_t)n0 * DMODEL;
    const float* bias = (p == 0) ? bq : (p == 1) ? bk : bv;
    const float scl   = (p == 0) ? QSCALE : 1.0f;

    const int wm = (wv & 1) * 64, wn = (wv >> 1) * 64;
    floatx4 acc[4][4] = {};
    const int ar = tid >> 1, ac = (tid & 1) * 16;

    uint4 pa0, pa1, pb0, pb1;
    pa0 = *(const uint4*)(xb + (size_t)(m0 + ar) * DMODEL + ac);
    pa1 = *(const uint4*)(xb + (size_t)(m0 + ar) * DMODEL + ac + 8);
    pb0 = *(const uint4*)(Wp + (size_t)ar * DMODEL + ac);
    pb1 = *(const uint4*)(Wp + (size_t)ar * DMODEL + ac + 8);

    for (int k0 = 0; k0 < DMODEL; k0 += 32) {
        *(uint4*)&A[ar][ac] = pa0; *(uint4*)&A[ar][ac + 8] = pa1;
        *(uint4*)&B[ar][ac] = pb0; *(uint4*)&B[ar][ac + 8] = pb1;
        __syncthreads();

        if (k0 + 32 < DMODEL) {
            pa0 = *(const uint4*)(xb + (size_t)(m0 + ar) * DMODEL + k0 + 32 + ac);
            pa1 = *(const uint4*)(xb + (size_t)(m0 + ar) * DMODEL + k0 + 32 + ac + 8);
            pb0 = *(const uint4*)(Wp + (size_t)ar * DMODEL + k0 + 32 + ac);
            pb1 = *(const uint4*)(Wp + (size_t)ar * DMODEL + k0 + 32 + ac + 8);
        }

        short8 af[4], bf[4];
        #pragma unroll
        for (int i = 0; i < 4; ++i) af[i] = *(const short8*)&A[wm + i * 16 + l16][quad * 8];
        #pragma unroll
        for (int c = 0; c < 4; ++c) bf[c] = *(const short8*)&B[wn + c * 16 + l16][quad * 8];
        #pragma unroll
        for (int i = 0; i < 4; ++i)
            #pragma unroll
            for (int c = 0; c < 4; ++c)
                acc[i][c] = __builtin_amdgcn_mfma_f32_16x16x32_bf16(af[i], bf[c], acc[i][c], 0, 0, 0);
        __syncthreads();
    }

    if (p < 2) {
        #pragma unroll
        for (int c = 0; c < 4; ++c) {
            const int n = n0 + wn + c * 16 + l16;
            const float bb = bias[n];
            const int h = n >> 6, dh = n & 63;
            #pragma unroll
            for (int i = 0; i < 4; ++i)
                #pragma unroll
                for (int r = 0; r < 4; ++r) {
                    const int m = m0 + wm + i * 16 + quad * 4 + r;
                    const int b = m >> 11, s = m & 2047;
                    const ushort val = f2bf((acc[i][c][r] + bb) * scl);
                    if (p == 0) q[((size_t)(b * NHEADS + h) * S_LEN + s) * DHEAD + dh] = val;
                    else        k[((size_t)(b * NHEADS + h) * S_LEN + s) * DHEAD + dh] = val;
                }
        }
    } else {
        #pragma unroll
        for (int c = 0; c < 4; ++c) {
            const int n = wn + c * 16 + l16;
            const float bb = bias[n0 + n];
            #pragma unroll
            for (int i = 0; i < 4; ++i) {
                uint2 o;
                o.x = pk2(acc[i][c][0] + bb, acc[i][c][1] + bb);
                o.y = pk2(acc[i][c][2] + bb, acc[i][c][3] + bb);
                *(uint2*)&CT[n][wm + i * 16 + quad * 4] = o;
            }
        }
        __syncthreads();
        const int n  = tid >> 1, mh = (tid & 1) * 64;
        const int gn = n0 + n;
        const int h  = gn >> 6, dh = gn & 63;
        const int b  = m0 >> 11, sb = (m0 & 2047) + mh;
        ushort* dst = vT + ((size_t)(b * NHEADS + h) * DHEAD + dh) * S_LEN + sb;
        #pragma unroll
        for (int j = 0; j < 8; ++j)
            *(uint4*)(dst + j * 8) = *(const uint4*)&CT[n][mh + j * 8];
    }
}

// ---------------------------------------------------------------------------
// Kernel 2: flash attention — r2 structure + 2-stage S/PV software pipeline,
// RULE-#20 SAFE this time: four NAMED floatx4 pairs (sA0..sA3 / sB0..sB3),
// straight-line macro expansion, zero runtime-indexed register arrays
// (r10's sv[cur] went to scratch: WRITE_SIZE 8.2->18.3 MB, 82 µs).
// Schedule per kt: QK(0) QK(1) PV(0) QK(2) PV(1) QK(3) PV(2) PV(3) —
// 4 independent S-MFMAs between each S-tile's production and its exp2
// consumption.  Numerically bit-identical to r2.
// ---------------------------------------------------------------------------
__global__ __launch_bounds__(256, 4) void attn(
    const ushort* __restrict__ Q, const ushort* __restrict__ K,
    const ushort* __restrict__ vT,
    ushort* __restrict__ att, const int KT)
{
    __shared__ ushort Klds[2][64][72];
    __shared__ ushort Vt[2][64][72];

    const int tid = threadIdx.x;
    const int wv  = tid >> 6, lane = tid & 63, l16 = lane & 15, quad = lane >> 4;
    const int q0  = blockIdx.x * 128;
    const int bh  = blockIdx.y;
    const ushort* Qh = Q  + (size_t)bh * S_LEN * DHEAD;
    const ushort* Kh = K  + (size_t)bh * S_LEN * DHEAD;
    const ushort* Vh = vT + (size_t)bh * DHEAD * S_LEN;

    short8 qf[2][2];
    #pragma unroll
    for (int ni = 0; ni < 2; ++ni) {
        const ushort* qrow = Qh + (size_t)(q0 + wv * 32 + ni * 16 + l16) * DHEAD;
        qf[0][ni] = *(const short8*)(qrow + quad * 8);
        qf[1][ni] = *(const short8*)(qrow + 32 + quad * 8);
    }

    floatx4 oacc[4][2] = {};   // O^T: [dh-tile][q-tile]
    float lsum[2] = {0.f, 0.f};

    const int srow = tid >> 2, sc0 = (tid & 3) * 16;
    uint4 ka, kb, va, vb;
    {
        const ushort* Ks = Kh + (size_t)srow * DHEAD + sc0;
        const ushort* Vs = Vh + (size_t)srow * S_LEN + sc0;
        ka = *(const uint4*)Ks; kb = *(const uint4*)(Ks + 8);
        va = *(const uint4*)Vs; vb = *(const uint4*)(Vs + 8);
    }

    for (int kt = 0; kt < KT; ++kt) {
        const int buf = kt & 1;
        *(uint4*)&Klds[buf][srow][sc0] = ka; *(uint4*)&Klds[buf][srow][sc0 + 8] = kb;
        *(uint4*)&Vt[buf][srow][sc0]   = va; *(uint4*)&Vt[buf][srow][sc0 + 8]   = vb;
        __syncthreads();   // sole barrier: dbuf makes the tail barrier unnecessary

        if (kt + 1 < KT) {
            const ushort* Ks = Kh + (size_t)((kt + 1) * 64 + srow) * DHEAD + sc0;
            const ushort* Vs = Vh + (size_t)srow * S_LEN + (kt + 1) * 64 + sc0;
            ka = *(const uint4*)Ks; kb = *(const uint4*)(Ks + 8);
            va = *(const uint4*)Vs; vb = *(const uint4*)(Vs + 8);
        }

        floatx4 sA0, sB0, sA1, sB1, sA2, sB2, sA3, sB3;

#define QK_STEP(MI, SA, SB) do {                                               \
        short8 kf0 = *(const short8*)&Klds[buf][(MI) * 16 + l16][quad * 8];    \
        short8 kf1 = *(const short8*)&Klds[buf][(MI) * 16 + l16][32 + quad * 8]; \
        SA = (floatx4){0.f, 0.f, 0.f, 0.f};                                    \
        SB = (floatx4){0.f, 0.f, 0.f, 0.f};                                    \
        SA = __builtin_amdgcn_mfma_f32_16x16x32_bf16(kf0, qf[0][0], SA, 0, 0, 0); \
        SA = __builtin_amdgcn_mfma_f32_16x16x32_bf16(kf1, qf[1][0], SA, 0, 0, 0); \
        SB = __builtin_amdgcn_mfma_f32_16x16x32_bf16(kf0, qf[0][1], SB, 0, 0, 0); \
        SB = __builtin_amdgcn_mfma_f32_16x16x32_bf16(kf1, qf[1][1], SB, 0, 0, 0); \
    } while (0)

#define PV_STEP(MI, SA, SB) do {                                               \
        short4v v0 = *(const short4v*)&Vt[buf][ 0 + l16][(MI) * 16 + quad * 4]; \
        short4v v1 = *(const short4v*)&Vt[buf][16 + l16][(MI) * 16 + quad * 4]; \
        short4v v2 = *(const short4v*)&Vt[buf][32 + l16][(MI) * 16 + quad * 4]; \
        short4v v3 = *(const short4v*)&Vt[buf][48 + l16][(MI) * 16 + quad * 4]; \
        float p0 = __builtin_amdgcn_exp2f(SA[0]);                              \
        float p1 = __builtin_amdgcn_exp2f(SA[1]);                              \
        float p2 = __builtin_amdgcn_exp2f(SA[2]);                              \
        float p3 = __builtin_amdgcn_exp2f(SA[3]);                              \
        lsum[0] += (p0 + p1) + (p2 + p3);                                      \
        uint2 oo; oo.x = pkr2(p0, p1); oo.y = pkr2(p2, p3);                    \
        short4v pf; *(uint2*)&pf = oo;                                         \
        oacc[0][0] = __builtin_amdgcn_mfma_f32_16x16x16bf16_1k(v0, pf, oacc[0][0], 0, 0, 0); \
        oacc[1][0] = __builtin_amdgcn_mfma_f32_16x16x16bf16_1k(v1, pf, oacc[1][0], 0, 0, 0); \
        oacc[2][0] = __builtin_amdgcn_mfma_f32_16x16x16bf16_1k(v2, pf, oacc[2][0], 0, 0, 0); \
        oacc[3][0] = __builtin_amdgcn_mfma_f32_16x16x16bf16_1k(v3, pf, oacc[3][0], 0, 0, 0); \
        p0 = __builtin_amdgcn_exp2f(SB[0]);                                    \
        p1 = __builtin_amdgcn_exp2f(SB[1]);                                    \
        p2 = __builtin_amdgcn_exp2f(SB[2]);                                    \
        p3 = __builtin_amdgcn_exp2f(SB[3]);                                    \
        lsum[1] += (p0 + p1) + (p2 + p3);                                      \
        oo.x = pkr2(p0, p1); oo.y = pkr2(p2, p3);                              \
        *(uint2*)&pf = oo;                                                     \
        oacc[0][1] = __builtin_amdgcn_mfma_f32_16x16x16bf16_1k(v0, pf, oacc[0][1], 0, 0, 0); \
        oacc[1][1] = __builtin_amdgcn_mfma_f32_16x16x16bf16_1k(v1, pf, oacc[1][1], 0, 0, 0); \
        oacc[2][1] = __builtin_amdgcn_mfma_f32_16x16x16bf16_1k(v2, pf, oacc[2][1], 0, 0, 0); \
        oacc[3][1] = __builtin_amdgcn_mfma_f32_16x16x16bf16_1k(v3, pf, oacc[3][1], 0, 0, 0); \
    } while (0)

        QK_STEP(0, sA0, sB0);
        QK_STEP(1, sA1, sB1);   // in flight while PV(0) runs exp2/pack
        PV_STEP(0, sA0, sB0);
        QK_STEP(2, sA2, sB2);
        PV_STEP(1, sA1, sB1);
        QK_STEP(3, sA3, sB3);
        PV_STEP(2, sA2, sB2);
        PV_STEP(3, sA3, sB3);

#undef QK_STEP
#undef PV_STEP
    }

    // full-row softmax denominators (quad-reduce over key groups)
    float rin[2];
    #pragma unroll
    for (int ni = 0; ni < 2; ++ni) {
        float t = lsum[ni];
        t += __shfl_xor(t, 16, 64);
        t += __shfl_xor(t, 32, 64);
        rin[ni] = 1.0f / t;
    }

    // normalized bf16 output, [B,S,H*Dh] row-major (= A matrix of out_gemm)
    const int b = bh >> 3, h = bh & 7;
    #pragma unroll
    for (int ni = 0; ni < 2; ++ni) {
        const int qg = q0 + wv * 32 + ni * 16 + l16;
        ushort* orow = att + ((size_t)(b * S_LEN + qg)) * DMODEL + h * DHEAD + quad * 4;
        #pragma unroll
        for (int c = 0; c < 4; ++c) {
            uint2 o;
            o.x = pk2(oacc[c][ni][0] * rin[ni], oacc[c][ni][1] * rin[ni]);
            o.y = pk2(oacc[c][ni][2] * rin[ni], oacc[c][ni][3] * rin[ni]);
            *(uint2*)(orow + c * 16) = o;
        }
    }
}

// ---------------------------------------------------------------------------
// Kernel 3: output projection — r4 version verbatim (padded LDS, uint4
// register prefetch).  Tile 64(M)x128(N) -> 512 blocks.
// ---------------------------------------------------------------------------
__global__ __launch_bounds__(256, 4) void out_gemm(
    const ushort* __restrict__ att,
    const ushort* __restrict__ WoT, const float* __restrict__ bo,
    float* __restrict__ out)
{
    __shared__ ushort A[64][40];
    __shared__ ushort B[128][40];

    const int tid = threadIdx.x;
    const int wv  = tid >> 6, lane = tid & 63, l16 = lane & 15, quad = lane >> 4;
    const int m0 = blockIdx.x * 64;
    const int n0 = blockIdx.y * 128;

    const int ar = tid >> 2, ac = (tid & 3) * 8;
    const int br = tid >> 1, bc = (tid & 1) * 16;

    floatx4 acc[8] = {};

    uint4 pa, pb0, pb1;
    pa  = *(const uint4*)(att + (size_t)(m0 + ar) * DMODEL + ac);
    pb0 = *(const uint4*)(WoT + (size_t)(n0 + br) * DMODEL + bc);
    pb1 = *(const uint4*)(WoT + (size_t)(n0 + br) * DMODEL + bc + 8);

    for (int k0 = 0; k0 < DMODEL; k0 += 32) {
        *(uint4*)&A[ar][ac] = pa;
        *(uint4*)&B[br][bc] = pb0; *(uint4*)&B[br][bc + 8] = pb1;
        __syncthreads();

        if (k0 + 32 < DMODEL) {
            pa  = *(const uint4*)(att + (size_t)(m0 + ar) * DMODEL + k0 + 32 + ac);
            pb0 = *(const uint4*)(WoT + (size_t)(n0 + br) * DMODEL + k0 + 32 + bc);
            pb1 = *(const uint4*)(WoT + (size_t)(n0 + br) * DMODEL + k0 + 32 + bc + 8);
        }

        short8 af = *(const short8*)&A[wv * 16 + l16][quad * 8];
        #pragma unroll
        for (int c = 0; c < 8; ++c) {
            short8 bf = *(const short8*)&B[c * 16 + l16][quad * 8];
            acc[c] = __builtin_amdgcn_mfma_f32_16x16x32_bf16(af, bf, acc[c], 0, 0, 0);
        }
        __syncthreads();
    }

    #pragma unroll
    for (int c = 0; c < 8; ++c) {
        const int n = n0 + c * 16 + l16;
        const float bb = bo[n];
        #pragma unroll
        for (int r = 0; r < 4; ++r) {
            const int m = m0 + wv * 16 + quad * 4 + r;
            out[(size_t)m * DMODEL + n] = acc[c][r] + bb;
        }
    }
}

// ---------------------------------------------------------------------------
extern "C" void kernel_launch(void* const* d_in, const int* in_sizes, int n_in,
                              void* d_out, int out_size, void* d_ws, size_t ws_size,
                              hipStream_t stream)
{
    const float* x  = (const float*)d_in[0];
    const float* Wq = (const float*)d_in[1];
    const float* bq = (const float*)d_in[2];
    const float* Wk = (const float*)d_in[3];
    const float* bk = (const float*)d_in[4];
    const float* Wv = (const float*)d_in[5];
    const float* bv = (const float*)d_in[6];
    const float* Wo = (const float*)d_in[7];
    const float* bo = (const float*)d_in[8];
    float* out = (float*)d_out;

    ushort* ws = (ushort*)d_ws;
    const size_t SZ = (size_t)M_TOT * DMODEL;
    ushort* xb  = ws;
    ushort* WT  = ws + SZ;
    ushort* q   = WT + 4 * (size_t)DMODEL * DMODEL;
    ushort* k   = q + SZ;
    ushort* vT  = k + SZ;
    ushort* att = vT + SZ;      // [B,S,H*Dh] bf16, normalized attention output

    prep<<<4096 + 256, 256, 0, stream>>>(x, Wq, Wk, Wv, Wo, xb, WT);

    qkv_gemm<<<dim3(M_TOT / 128, 3 * DMODEL / 128), 256, 0, stream>>>(
        xb, WT, bq, bk, bv, q, k, vT);

    attn<<<dim3(S_LEN / 128, BATCH * NHEADS), 256, 0, stream>>>(
        q, k, vT, att, S_LEN / 64);

    out_gemm<<<dim3(M_TOT / 64, DMODEL / 128), 256, 0, stream>>>(
        att, WT + 3 * (size_t)DMODEL * DMODEL, bo, out);
}